// Round 1
// baseline (521.316 us; speedup 1.0000x reference)
//
#include <hip/hip_runtime.h>

// Mean aggregation over K sampled neighbors:
//   out[b, :] = (1/K) * sum_k embed[idx[b,k], :]
// B=100000, K=32, N=500000, D=128 fp32.
//
// One node per 32-lane group (float4 across D=128 -> 32 vec4 slots).
// 256-thread block = 8 nodes. Indices staged in LDS. Fully unrolled K loop
// gives 32 independent float4 loads per thread for latency hiding.

constexpr int K = 32;
constexpr int D = 128;
constexpr int VEC = D / 4;          // 32 float4 per row
constexpr int NODES_PER_BLOCK = 8;  // 256 threads / 32 lanes per node
constexpr int BLOCK = NODES_PER_BLOCK * VEC;  // 256

__global__ __launch_bounds__(BLOCK)
void mean_agg_kernel(const float4* __restrict__ embed,
                     const int* __restrict__ idx,
                     float4* __restrict__ out,
                     int B) {
    __shared__ int s_idx[NODES_PER_BLOCK * K];

    const int tid  = threadIdx.x;
    const int node = tid >> 5;   // 0..7  (which node in this block)
    const int vec  = tid & 31;   // 0..31 (float4 slot within the row)
    const int b0   = blockIdx.x * NODES_PER_BLOCK;

    // Stage this block's 8*32 indices (coalesced int loads).
    const long long gidx = (long long)b0 * K + tid;
    if (gidx < (long long)B * K) {
        s_idx[tid] = idx[gidx];
    }
    __syncthreads();

    const int b = b0 + node;
    if (b >= B) return;

    float4 sum = make_float4(0.f, 0.f, 0.f, 0.f);
#pragma unroll
    for (int k = 0; k < K; ++k) {
        const size_t row = (size_t)s_idx[node * K + k];
        const float4 v = embed[row * VEC + vec];
        sum.x += v.x;
        sum.y += v.y;
        sum.z += v.z;
        sum.w += v.w;
    }

    const float inv = 1.0f / (float)K;
    float4 r;
    r.x = sum.x * inv;
    r.y = sum.y * inv;
    r.z = sum.z * inv;
    r.w = sum.w * inv;
    out[(size_t)b * VEC + vec] = r;
}

extern "C" void kernel_launch(void* const* d_in, const int* in_sizes, int n_in,
                              void* d_out, int out_size, void* d_ws, size_t ws_size,
                              hipStream_t stream) {
    const float* embed = (const float*)d_in[0];
    const int*   idx   = (const int*)d_in[1];
    // d_in[2] = num_sample scalar; fixed at K=32 per problem setup.
    float* out = (float*)d_out;

    const int B = in_sizes[1] / K;  // neigh_idx flat count = B*K

    dim3 grid((B + NODES_PER_BLOCK - 1) / NODES_PER_BLOCK);
    mean_agg_kernel<<<grid, BLOCK, 0, stream>>>(
        (const float4*)embed, idx, (float4*)out, B);
}

// Round 2
// 521.041 us; speedup vs baseline: 1.0005x; 1.0005x over previous
//
#include <hip/hip_runtime.h>

// Mean aggregation over K sampled neighbors:
//   out[b, :] = (1/K) * sum_k embed[idx[b,k], :]
// B=100000, K=32, N=500000, D=128 fp32.
//
// R1: latency-bound fix. Batch the K loop into groups of 8 explicit float4
// temporaries so 8 loads are in flight before first use (MLP=8 per thread).
// __launch_bounds__(256, 8) -> VGPR cap 64 -> still 32 waves/CU possible.
// Row byte offsets fit in 32 bits (500k * 512B = 256MB), so the compiler can
// use sgpr-base + 32-bit voffset addressing (1 VGPR per address).

constexpr int K = 32;
constexpr int D = 128;
constexpr int VEC = D / 4;          // 32 float4 per row
constexpr int NODES_PER_BLOCK = 8;  // 256 threads / 32 lanes per node
constexpr int BLOCK = NODES_PER_BLOCK * VEC;  // 256
constexpr int MLP = 8;              // loads in flight per thread

__global__ __launch_bounds__(BLOCK, 8)
void mean_agg_kernel(const float4* __restrict__ embed,
                     const int* __restrict__ idx,
                     float4* __restrict__ out,
                     int B) {
    __shared__ int s_idx[NODES_PER_BLOCK * K];

    const int tid  = threadIdx.x;
    const int node = tid >> 5;   // 0..7
    const int vec  = tid & 31;   // 0..31
    const int b0   = blockIdx.x * NODES_PER_BLOCK;

    const long long gidx = (long long)b0 * K + tid;
    if (gidx < (long long)B * K) {
        s_idx[tid] = idx[gidx];
    }
    __syncthreads();

    const int b = b0 + node;
    if (b >= B) return;

    float4 sum = make_float4(0.f, 0.f, 0.f, 0.f);

#pragma unroll
    for (int kk = 0; kk < K; kk += MLP) {
        // Pull the 8 row indices first (LDS reads, broadcast within group).
        unsigned r[MLP];
#pragma unroll
        for (int j = 0; j < MLP; ++j) {
            r[j] = (unsigned)s_idx[node * K + kk + j];
        }
        // Issue 8 independent float4 loads before any use.
        float4 v[MLP];
#pragma unroll
        for (int j = 0; j < MLP; ++j) {
            v[j] = embed[(size_t)r[j] * VEC + vec];
        }
#pragma unroll
        for (int j = 0; j < MLP; ++j) {
            sum.x += v[j].x;
            sum.y += v[j].y;
            sum.z += v[j].z;
            sum.w += v[j].w;
        }
    }

    const float inv = 1.0f / (float)K;
    float4 r;
    r.x = sum.x * inv;
    r.y = sum.y * inv;
    r.z = sum.z * inv;
    r.w = sum.w * inv;
    out[(size_t)b * VEC + vec] = r;
}

extern "C" void kernel_launch(void* const* d_in, const int* in_sizes, int n_in,
                              void* d_out, int out_size, void* d_ws, size_t ws_size,
                              hipStream_t stream) {
    const float* embed = (const float*)d_in[0];
    const int*   idx   = (const int*)d_in[1];
    float* out = (float*)d_out;

    const int B = in_sizes[1] / K;

    dim3 grid((B + NODES_PER_BLOCK - 1) / NODES_PER_BLOCK);
    mean_agg_kernel<<<grid, BLOCK, 0, stream>>>(
        (const float4*)embed, idx, (float4*)out, B);
}

// Round 3
// 517.948 us; speedup vs baseline: 1.0065x; 1.0060x over previous
//
#include <hip/hip_runtime.h>

// Mean aggregation: out[b,:] = (1/K) * sum_k embed[idx[b,k],:]
// B=100000, K=32, N=500000, D=128 fp32.
//
// R2 restructure: one WAVE per node. All 64 lanes read the same row
// (lane -> float2 slot, 64*8B = 512B = one row). Row index is wave-uniform
// (forced via readfirstlane) so the 32 indices load via SCALAR loads into
// SGPRs once, and every gather is an saddr-form global_load_dwordx2 with a
// loop-invariant vector offset. No LDS, no per-k lgkmcnt dependency, fully
// independent load chain -> deep MLP. One 512B segment per wave-load
// (vs 2 before) halves per-request line/MSHR pressure.

constexpr int K = 32;
constexpr int D = 128;
constexpr int WAVES_PER_BLOCK = 4;
constexpr int BLOCK = WAVES_PER_BLOCK * 64;  // 256

__global__ __launch_bounds__(BLOCK, 8)
void mean_agg_kernel(const float* __restrict__ embed,
                     const int* __restrict__ idx,
                     float* __restrict__ out,
                     int B) {
    const int tid  = threadIdx.x;
    const int lane = tid & 63;              // float2 slot within the row

    int b = blockIdx.x * WAVES_PER_BLOCK + (tid >> 6);
    b = __builtin_amdgcn_readfirstlane(b);  // wave-uniform node id
    if (b >= B) return;

    // Wave-uniform index pointer -> compiler emits scalar (s_load) reads.
    const int* __restrict__ idx_b = idx + (size_t)b * K;
    int rows[K];
#pragma unroll
    for (int k = 0; k < K; ++k) {
        rows[k] = idx_b[k];                 // uniform -> SGPRs
    }

    float2 acc[4];
    acc[0] = acc[1] = acc[2] = acc[3] = make_float2(0.f, 0.f);

#pragma unroll
    for (int kk = 0; kk < K; kk += 8) {
        float2 v[8];
#pragma unroll
        for (int j = 0; j < 8; ++j) {
            const float2* __restrict__ rp =
                (const float2*)(embed + (size_t)(unsigned)rows[kk + j] * D);
            v[j] = rp[lane];                // saddr-form, independent
        }
#pragma unroll
        for (int j = 0; j < 8; ++j) {
            acc[j & 3].x += v[j].x;
            acc[j & 3].y += v[j].y;
        }
    }

    const float inv = 1.0f / (float)K;
    float2 r;
    r.x = (acc[0].x + acc[1].x + acc[2].x + acc[3].x) * inv;
    r.y = (acc[0].y + acc[1].y + acc[2].y + acc[3].y) * inv;

    ((float2*)(out + (size_t)b * D))[lane] = r;
}

extern "C" void kernel_launch(void* const* d_in, const int* in_sizes, int n_in,
                              void* d_out, int out_size, void* d_ws, size_t ws_size,
                              hipStream_t stream) {
    const float* embed = (const float*)d_in[0];
    const int*   idx   = (const int*)d_in[1];
    float* out = (float*)d_out;

    const int B = in_sizes[1] / K;

    dim3 grid((B + WAVES_PER_BLOCK - 1) / WAVES_PER_BLOCK);
    mean_agg_kernel<<<grid, BLOCK, 0, stream>>>(embed, idx, out, B);
}

// Round 4
// 516.656 us; speedup vs baseline: 1.0090x; 1.0025x over previous
//
#include <hip/hip_runtime.h>

// Mean aggregation: out[b,:] = (1/K) * sum_k embed[idx[b,k],:]
// B=100000, K=32, N=500000, D=128 fp32.
//
// R3: keep the 256-MB embed table resident in the 256-MB Infinity Cache.
// The output stream (51 MB/iter) is single-use: store it NONTEMPORAL so it
// doesn't allocate L2/L3 lines and evict table rows. Structure otherwise
// identical to R2 (one wave per node, indices in SGPRs, saddr-form
// global_load_dwordx2 gathers, deep independent load chain).

constexpr int K = 32;
constexpr int D = 128;
constexpr int WAVES_PER_BLOCK = 4;
constexpr int BLOCK = WAVES_PER_BLOCK * 64;  // 256

typedef float vfloat2 __attribute__((ext_vector_type(2)));

__global__ __launch_bounds__(BLOCK, 8)
void mean_agg_kernel(const float* __restrict__ embed,
                     const int* __restrict__ idx,
                     float* __restrict__ out,
                     int B) {
    const int tid  = threadIdx.x;
    const int lane = tid & 63;              // float2 slot within the row

    int b = blockIdx.x * WAVES_PER_BLOCK + (tid >> 6);
    b = __builtin_amdgcn_readfirstlane(b);  // wave-uniform node id
    if (b >= B) return;

    // Wave-uniform index pointer -> scalar (s_load) reads into SGPRs.
    const int* __restrict__ idx_b = idx + (size_t)b * K;
    int rows[K];
#pragma unroll
    for (int k = 0; k < K; ++k) {
        rows[k] = idx_b[k];
    }

    float2 acc[4];
    acc[0] = acc[1] = acc[2] = acc[3] = make_float2(0.f, 0.f);

#pragma unroll
    for (int kk = 0; kk < K; kk += 8) {
        float2 v[8];
#pragma unroll
        for (int j = 0; j < 8; ++j) {
            const float2* __restrict__ rp =
                (const float2*)(embed + (size_t)(unsigned)rows[kk + j] * D);
            v[j] = rp[lane];                // saddr-form, independent
        }
#pragma unroll
        for (int j = 0; j < 8; ++j) {
            acc[j & 3].x += v[j].x;
            acc[j & 3].y += v[j].y;
        }
    }

    const float inv = 1.0f / (float)K;
    vfloat2 r;
    r.x = (acc[0].x + acc[1].x + acc[2].x + acc[3].x) * inv;
    r.y = (acc[0].y + acc[1].y + acc[2].y + acc[3].y) * inv;

    // Nontemporal store: don't let the 51-MB output stream evict table
    // lines from L2/Infinity Cache.
    vfloat2* op = (vfloat2*)(out + (size_t)b * D) + lane;
    __builtin_nontemporal_store(r, op);
}

extern "C" void kernel_launch(void* const* d_in, const int* in_sizes, int n_in,
                              void* d_out, int out_size, void* d_ws, size_t ws_size,
                              hipStream_t stream) {
    const float* embed = (const float*)d_in[0];
    const int*   idx   = (const int*)d_in[1];
    float* out = (float*)d_out;

    const int B = in_sizes[1] / K;

    dim3 grid((B + WAVES_PER_BLOCK - 1) / WAVES_PER_BLOCK);
    mean_agg_kernel<<<grid, BLOCK, 0, stream>>>(embed, idx, out, B);
}